// Round 1
// baseline (80.403 us; speedup 1.0000x reference)
//
#include <hip/hip_runtime.h>

#define D   512
#define BSZ 128
#define HW  196   // 14*14

// ---------------------------------------------------------------------------
// K1: p[b,j] = sum_k m_prev[b,k] * W_m[k][j]  (+ b_m[j] once)
// grid (jt=2, bt=8, kt=8), block 256. Lanes map to j -> W_m reads coalesced.
// ---------------------------------------------------------------------------
__global__ void k_p(const float* __restrict__ m_prev, const float* __restrict__ W_m,
                    const float* __restrict__ b_m, float* __restrict__ p) {
    const int j  = blockIdx.x * 256 + threadIdx.x;   // 0..511
    const int b0 = blockIdx.y * 16;
    const int k0 = blockIdx.z * 64;
    __shared__ float xs[16][64];
    for (int i = threadIdx.x; i < 16 * 64; i += 256) {
        int bb = i >> 6, kk = i & 63;
        xs[bb][kk] = m_prev[(b0 + bb) * D + k0 + kk];
    }
    __syncthreads();
    float acc[16];
    #pragma unroll
    for (int bb = 0; bb < 16; ++bb) acc[bb] = 0.f;
    for (int kk = 0; kk < 64; ++kk) {
        float wv = W_m[(k0 + kk) * D + j];
        #pragma unroll
        for (int bb = 0; bb < 16; ++bb) acc[bb] += xs[bb][kk] * wv;
    }
    const float bias = (blockIdx.z == 0) ? b_m[j] : 0.f;
    #pragma unroll
    for (int bb = 0; bb < 16; ++bb)
        atomicAdd(&p[(b0 + bb) * D + j], acc[bb] + bias);
}

// ---------------------------------------------------------------------------
// K2: t12[b,kk] = sum_j u[b,j] * W_merge[kk][j],  kk in [0,1024), u = c*W_attn
// grid (kkt=4, bt=8, jt=8), block 256. Per-lane float4 row reads of W_merge.
// ---------------------------------------------------------------------------
__global__ void k_t12(const float* __restrict__ c, const float* __restrict__ W_attn,
                      const float* __restrict__ W_merge, float* __restrict__ t12) {
    const int kk = blockIdx.x * 256 + threadIdx.x;   // 0..1023
    const int b0 = blockIdx.y * 16;
    const int j0 = blockIdx.z * 64;
    __shared__ float us[16][64];
    for (int i = threadIdx.x; i < 16 * 64; i += 256) {
        int bb = i >> 6, jj = i & 63;
        us[bb][jj] = c[(b0 + bb) * D + j0 + jj] * W_attn[j0 + jj];
    }
    __syncthreads();
    float acc[16];
    #pragma unroll
    for (int bb = 0; bb < 16; ++bb) acc[bb] = 0.f;
    const float4* wrow = (const float4*)&W_merge[kk * D + j0];
    for (int q = 0; q < 16; ++q) {
        float4 w4 = wrow[q];
        #pragma unroll
        for (int bb = 0; bb < 16; ++bb) {
            acc[bb] += us[bb][4*q+0] * w4.x + us[bb][4*q+1] * w4.y
                     + us[bb][4*q+2] * w4.z + us[bb][4*q+3] * w4.w;
        }
    }
    #pragma unroll
    for (int bb = 0; bb < 16; ++bb)
        atomicAdd(&t12[(b0 + bb) * 1024 + kk], acc[bb]);
}

// ---------------------------------------------------------------------------
// K3: w[b,k'] = sum_k W_kb[k'][k] * r[b,k]  (+ t2[b,k'] once),  r = p .* t1
// grid (kpt=2, bt=8, kt=8), block 256.
// ---------------------------------------------------------------------------
__global__ void k_w(const float* __restrict__ p, const float* __restrict__ t12,
                    const float* __restrict__ W_kb, float* __restrict__ w) {
    const int kp = blockIdx.x * 256 + threadIdx.x;   // 0..511
    const int b0 = blockIdx.y * 16;
    const int k0 = blockIdx.z * 64;
    __shared__ float rs[16][64];
    for (int i = threadIdx.x; i < 16 * 64; i += 256) {
        int bb = i >> 6, kk = i & 63;
        int b = b0 + bb, k = k0 + kk;
        rs[bb][kk] = p[b * D + k] * t12[b * 1024 + k];   // t1 = cols [0,512)
    }
    __syncthreads();
    float acc[16];
    #pragma unroll
    for (int bb = 0; bb < 16; ++bb) acc[bb] = 0.f;
    const float4* wrow = (const float4*)&W_kb[kp * D + k0];
    for (int q = 0; q < 16; ++q) {
        float4 w4 = wrow[q];
        #pragma unroll
        for (int bb = 0; bb < 16; ++bb) {
            acc[bb] += rs[bb][4*q+0] * w4.x + rs[bb][4*q+1] * w4.y
                     + rs[bb][4*q+2] * w4.z + rs[bb][4*q+3] * w4.w;
        }
    }
    #pragma unroll
    for (int bb = 0; bb < 16; ++bb) {
        float extra = (blockIdx.z == 0) ? t12[(b0 + bb) * 1024 + 512 + kp] : 0.f;
        atomicAdd(&w[(b0 + bb) * D + kp], acc[bb] + extra);
    }
}

// ---------------------------------------------------------------------------
// Kbeta: beta[b] = sum_j (b_merge[j]*u[b,j] + b_kb[j]*r[b,j]) + b_attn
// grid 128, block 256.
// ---------------------------------------------------------------------------
__global__ void k_beta(const float* __restrict__ c, const float* __restrict__ W_attn,
                       const float* __restrict__ b_merge, const float* __restrict__ b_kb,
                       const float* __restrict__ b_attn, const float* __restrict__ p,
                       const float* __restrict__ t12, float* __restrict__ beta) {
    const int b = blockIdx.x;
    const int t = threadIdx.x;
    float s = 0.f;
    for (int j = t; j < D; j += 256) {
        float u = c[b * D + j] * W_attn[j];
        float r = p[b * D + j] * t12[b * 1024 + j];
        s += b_merge[j] * u + b_kb[j] * r;
    }
    #pragma unroll
    for (int off = 32; off; off >>= 1) s += __shfl_down(s, off, 64);
    __shared__ float red[4];
    if ((t & 63) == 0) red[t >> 6] = s;
    __syncthreads();
    if (t == 0) beta[b] = red[0] + red[1] + red[2] + red[3] + b_attn[0];
}

// ---------------------------------------------------------------------------
// K_MV: mv[b,hw] = sum_k KB[b,k,hw] * w[b,k] + beta[b]
// grid 512 (b * 4 k-chunks), block 256; lanes over hw -> coalesced KB reads.
// ---------------------------------------------------------------------------
__global__ void k_mv(const float* __restrict__ KB, const float* __restrict__ w,
                     const float* __restrict__ beta, float* __restrict__ mv) {
    const int b  = blockIdx.x >> 2;
    const int ks = blockIdx.x & 3;
    const int t  = threadIdx.x;
    __shared__ float wl[128];
    __shared__ float bl;
    if (t < 128) wl[t] = w[b * D + ks * 128 + t];
    if (t == 0)  bl = (ks == 0) ? beta[b] : 0.f;
    __syncthreads();
    if (t < HW) {
        const float* kbp = KB + (size_t)b * D * HW + (size_t)ks * 128 * HW + t;
        float acc = bl;
        #pragma unroll 8
        for (int k = 0; k < 128; ++k) acc += kbp[(size_t)k * HW] * wl[k];
        atomicAdd(&mv[b * HW + t], acc);
    }
}

// ---------------------------------------------------------------------------
// K_MNEW: out[b,k] = sum_hw KB[b,k,hw] * mv[b,hw]
// grid 256 (b * 2 k-halves), block 256; per-lane float4 row reads (L3-hot).
// ---------------------------------------------------------------------------
__global__ void k_mnew(const float* __restrict__ KB, const float* __restrict__ mv,
                       float* __restrict__ out) {
    const int b  = blockIdx.x >> 1;
    const int kh = blockIdx.x & 1;
    const int t  = threadIdx.x;
    __shared__ float ml[HW];
    if (t < HW) ml[t] = mv[b * HW + t];
    __syncthreads();
    const int k = kh * 256 + t;
    const float4* row = (const float4*)(KB + (size_t)b * D * HW + (size_t)k * HW);
    float acc = 0.f;
    #pragma unroll 7
    for (int h4 = 0; h4 < 49; ++h4) {
        float4 v = row[h4];
        acc += v.x * ml[4*h4+0] + v.y * ml[4*h4+1] + v.z * ml[4*h4+2] + v.w * ml[4*h4+3];
    }
    out[b * D + k] = acc;
}

// ---------------------------------------------------------------------------
extern "C" void kernel_launch(void* const* d_in, const int* in_sizes, int n_in,
                              void* d_out, int out_size, void* d_ws, size_t ws_size,
                              hipStream_t stream) {
    const float* m_prev  = (const float*)d_in[0];
    const float* KB      = (const float*)d_in[1];
    const float* c_i     = (const float*)d_in[2];
    const float* W_m     = (const float*)d_in[3];
    const float* b_m     = (const float*)d_in[4];
    const float* W_kb    = (const float*)d_in[5];
    const float* b_kb    = (const float*)d_in[6];
    const float* W_merge = (const float*)d_in[7];
    const float* b_merge = (const float*)d_in[8];
    const float* W_attn  = (const float*)d_in[9];
    const float* b_attn  = (const float*)d_in[10];
    float* out = (float*)d_out;

    float* ws   = (float*)d_ws;
    float* p    = ws;             // 65536
    float* t12  = ws + 65536;     // 131072 ([B][1024]: t1 | t2)
    float* w    = ws + 196608;    // 65536
    float* mv   = ws + 262144;    // 25088
    float* beta = ws + 287232;    // 128
    hipMemsetAsync(d_ws, 0, 287360 * sizeof(float), stream);

    k_p  <<<dim3(2, 8, 8), 256, 0, stream>>>(m_prev, W_m, b_m, p);
    k_t12<<<dim3(4, 8, 8), 256, 0, stream>>>(c_i, W_attn, W_merge, t12);
    k_w  <<<dim3(2, 8, 8), 256, 0, stream>>>(p, t12, W_kb, w);
    k_beta<<<128, 256, 0, stream>>>(c_i, W_attn, b_merge, b_kb, b_attn, p, t12, beta);
    k_mv <<<512, 256, 0, stream>>>(KB, w, beta, mv);
    k_mnew<<<256, 256, 0, stream>>>(KB, mv, out);
}